// Round 3
// baseline (448.654 us; speedup 1.0000x reference)
//
#include <hip/hip_runtime.h>

// Correlation volume, N=8, Z=128, H=W=160, 81 shifts (9 dy x 9 dx).
// v3 (resubmit; round-2 bench was an infra failure, no data):
// 3-wave blocks (dy-triple of a 16x32 tile), 1200 blocks (4.7/CU,
// self-balancing, XCD-swizzled: bid%8 = image), LDS staging via
// global_load_lds with prefetch distance 3 (NBUF=4), chunk = 1 z-slice.
// Combines round-0's staging mechanism with round-1's independence/balance.
#define NB 8
#define ZD 128
#define HD 160
#define WD 160
#define PLANE (HD * WD)            // 25600
#define IMG (ZD * PLANE)

#define TI 16
#define TJ 32
#define TILES_PER_IMG 50           // 10 x 5
#define DQ 3                       // dy-triples per tile -> 3 waves/block
#define NTHREADS 192

#define ASL 9                      // A 16B-slots/row (8 data + 1 pad)
#define BSL 11                     // B 16B-slots/row (10 data + 1 pad)
#define BROWS 18                   // dy-triple row window (16 + 2 halo)
#define A_SLOTS (TI * ASL)         // 144
#define B_SLOTS (BROWS * BSL)      // 198
#define BUF_SLOTS 384              // 342 real, padded to 2*192 (2 loads/thread)
#define NBUF 4                     // prefetch distance 3

#define GP(x) ((const __attribute__((address_space(1))) void*)(x))
#define LP(x) ((__attribute__((address_space(3))) void*)(x))

__global__ __launch_bounds__(NTHREADS, 4)
void corr_vol_kernel(const float* __restrict__ A, const float* __restrict__ B,
                     const float* __restrict__ zp, float* __restrict__ out) {
    __shared__ float4 lds[NBUF * BUF_SLOTS];   // 24.5 KB
    __shared__ float4 dump[64];                // sink for tail dummy loads

    const int tid = threadIdx.x;
    const int bid = blockIdx.x;
    const int x  = bid & 7;            // XCD = image
    const int s  = bid >> 3;           // 0..149
    const int tl = s / DQ;             // tile 0..49
    const int dq = s - DQ * tl;        // dy-triple 0..2
    const int n  = x;
    const int it = tl / 5, jt = tl - 5 * it;
    const int i0 = it * TI, j0 = jt * TJ;

    const float* Abase = A + (size_t)n * IMG;
    const float* Bbase = B + (size_t)n * IMG;

    // ---- staging descriptors: slots s1 = tid, s2 = tid + 192 ----
    // A region [0,144): row rA, slot cA (8 data + 1 pad).
    // B region [144,342): row rB in [0,18) = global row i0+3dq-4+rB,
    //                     slot cB (10 data + 1 pad), cols j0-4+4*cB.
    // pad/OOB slots -> zero page, stride 0.
    const float *p1, *p2; int st1, st2;
    {
        const int s1 = tid;
        if (s1 < A_SLOTS) {
            const int rA = s1 / ASL, cA = s1 % ASL;
            const bool v = (cA < 8);
            p1 = v ? Abase + (size_t)(i0 + rA) * WD + j0 + 4 * cA : zp;
            st1 = v ? PLANE : 0;
        } else {
            const int q = s1 - A_SLOTS;
            const int rB = q / BSL, cB = q % BSL;
            const int gr = i0 + 3 * dq - 4 + rB, gc = j0 - 4 + 4 * cB;
            const bool v = (cB < 10) && ((unsigned)gr < (unsigned)HD) &&
                           ((unsigned)gc < (unsigned)WD);
            p1 = v ? Bbase + (size_t)gr * WD + gc : zp;
            st1 = v ? PLANE : 0;
        }
        const int q2 = tid + NTHREADS - A_SLOTS;   // slot2 always in B/pad region
        const int rB2 = q2 / BSL, cB2 = q2 % BSL;
        const int gr2 = i0 + 3 * dq - 4 + rB2, gc2 = j0 - 4 + 4 * cB2;
        const bool v2 = (q2 < B_SLOTS) && (cB2 < 10) &&
                        ((unsigned)gr2 < (unsigned)HD) && ((unsigned)gc2 < (unsigned)WD);
        p2 = v2 ? Bbase + (size_t)gr2 * WD + gc2 : zp;
        st2 = v2 ? PLANE : 0;
    }
    const unsigned d1 = (unsigned)(tid & ~63);               // wave-uniform slot base
    const unsigned d2 = (unsigned)((tid + NTHREADS) & ~63);

    const float* pp1 = p1;   // running pointers (advance by one z per prefetch)
    const float* pp2 = p2;

    // Every thread issues EXACTLY 2 global_load_lds per prefetch -> exact vmcnt.
    auto prefetch = [&](int k2, int pb) {
        char* base = (char*)&lds[pb * BUF_SLOTS];
        if (k2 < ZD) {
            __builtin_amdgcn_global_load_lds(GP(pp1), LP(base + 16u * d1), 16, 0, 0);
            __builtin_amdgcn_global_load_lds(GP(pp2), LP(base + 16u * d2), 16, 0, 0);
            pp1 += st1; pp2 += st2;
        } else {  // tail dummies keep per-wave outstanding-count uniform
            __builtin_amdgcn_global_load_lds(GP(zp), LP((char*)&dump[0]), 16, 0, 0);
            __builtin_amdgcn_global_load_lds(GP(zp), LP((char*)&dump[0]), 16, 0, 0);
        }
    };

    const int wi = tid >> 6;           // 0..2 within the triple
    const int w  = 3 * dq + wi;        // dy index 0..8
    const int l  = tid & 63;
    const int r  = l >> 2;             // pixel row 0..15
    const int g  = l & 3;              // col group (8 cols)

    // LDS float offsets (constant per thread)
    const int aoff = ASL * 4 * r + 8 * g;                        // 36r + 8g
    const int boff = 4 * A_SLOTS + BSL * 4 * (r + wi) + 8 * g;   // 576 + 44(r+wi) + 8g

    float acc[9][8];
    #pragma unroll
    for (int d = 0; d < 9; ++d)
        #pragma unroll
        for (int p = 0; p < 8; ++p) acc[d][p] = 0.f;

    prefetch(0, 0);
    prefetch(1, 1);
    prefetch(2, 2);

#define STEP(k, rb, pb) do {                                                    \
    asm volatile("s_waitcnt vmcnt(4)\n\ts_barrier" ::: "memory");               \
    prefetch((k) + 3, (pb));                                                    \
    const float* Af = (const float*)&lds[(rb) * BUF_SLOTS];                     \
    float a[8], b[16];                                                          \
    *(float4*)&a[0]  = *(const float4*)(Af + aoff);                             \
    *(float4*)&a[4]  = *(const float4*)(Af + aoff + 4);                         \
    *(float4*)&b[0]  = *(const float4*)(Af + boff);                             \
    *(float4*)&b[4]  = *(const float4*)(Af + boff + 4);                         \
    *(float4*)&b[8]  = *(const float4*)(Af + boff + 8);                         \
    *(float4*)&b[12] = *(const float4*)(Af + boff + 12);                        \
    _Pragma("unroll")                                                           \
    for (int d = 0; d < 9; ++d)                                                 \
        _Pragma("unroll")                                                       \
        for (int p = 0; p < 8; ++p)                                             \
            acc[d][p] = fmaf(a[p], b[p + d], acc[d][p]);                        \
} while (0)

    for (int m = 0; m < ZD / 4; ++m) {
        const int k = 4 * m;
        STEP(k + 0, 0, 3);
        STEP(k + 1, 1, 0);
        STEP(k + 2, 2, 1);
        STEP(k + 3, 3, 2);
    }
#undef STEP

    asm volatile("s_waitcnt vmcnt(0)" ::: "memory");  // drain tail dummies

    // ---- epilogue: out[k = d*9 + w] (d = x-shift, w = y-shift) ----
    float* obase = out + (((size_t)n * 81) * HD + (i0 + r)) * WD + j0 + 8 * g;
    #pragma unroll
    for (int d = 0; d < 9; ++d) {
        const int kk = d * 9 + w;
        float* o = obase + (size_t)kk * PLANE;
        *(float4*)&o[0] = make_float4(acc[d][0], acc[d][1], acc[d][2], acc[d][3]);
        *(float4*)&o[4] = make_float4(acc[d][4], acc[d][5], acc[d][6], acc[d][7]);
    }
}

extern "C" void kernel_launch(void* const* d_in, const int* in_sizes, int n_in,
                              void* d_out, int out_size, void* d_ws, size_t ws_size,
                              hipStream_t stream) {
    const float* A = (const float*)d_in[0];
    const float* B = (const float*)d_in[1];
    float* out = (float*)d_out;
    // 256 B zero page for OOB/pad staging lanes (d_ws re-poisoned every launch).
    hipMemsetAsync(d_ws, 0, 256, stream);
    corr_vol_kernel<<<dim3(NB * TILES_PER_IMG * DQ), dim3(NTHREADS), 0, stream>>>(
        A, B, (const float*)d_ws, out);
}